// Round 2
// baseline (110.397 us; speedup 1.0000x reference)
//
#include <hip/hip_runtime.h>

// out[b,c,a,j] = mean_{4x4}( images[b,c, 4*((a - dy) % 56) .. +3,
//                                        4*((j - dx) % 56) .. +3] )
// with dy = W_shifts[b], dx = H_shifts[b] (kornia arg swap).
//
// 4 outputs per thread (one float4 store, 16B/lane). Reads: 16 float4 loads
// per thread, each input byte touched exactly once, coalesced (row stride
// 224 floats = 896 B; consecutive lanes hit consecutive 64 B source spans
// except at the single wrap point per row).

__global__ __launch_bounds__(256) void ds_wrap_translate_kernel(
    const float* __restrict__ images,
    const int*   __restrict__ H_shifts,
    const int*   __restrict__ W_shifts,
    float4*      __restrict__ out)
{
    constexpr int C = 3, W = 224, h = 56, w = 56, wq = 14;  // wq = w/4

    int tid = blockIdx.x * 256 + threadIdx.x;   // grid is exact: 1176*256 = 301056

    int jq = tid % wq;
    int t1 = tid / wq;
    int a  = t1 % h;
    int bc = t1 / h;        // b*C + c, 0..383
    int b  = bc / C;

    int dy = W_shifts[b];   // height shift
    int dx = H_shifts[b];   // width shift

    int sa = a - dy; if (sa < 0) sa += h;
    const float* rowbase = images + ((size_t)bc * 224 + 4 * sa) * W;

    int sj = 4 * jq - dx; if (sj < 0) sj += w;

    float acc[4];
    #pragma unroll
    for (int k = 0; k < 4; ++k) {
        const float* p = rowbase + 4 * sj;
        float4 r0 = *(const float4*)(p);
        float4 r1 = *(const float4*)(p + W);
        float4 r2 = *(const float4*)(p + 2 * W);
        float4 r3 = *(const float4*)(p + 3 * W);
        acc[k] = ((r0.x + r0.y + r0.z + r0.w)
                + (r1.x + r1.y + r1.z + r1.w)
                + (r2.x + r2.y + r2.z + r2.w)
                + (r3.x + r3.y + r3.z + r3.w)) * (1.0f / 16.0f);
        ++sj; if (sj == w) sj = 0;   // columns advance cyclically
    }

    out[tid] = make_float4(acc[0], acc[1], acc[2], acc[3]);
}

extern "C" void kernel_launch(void* const* d_in, const int* in_sizes, int n_in,
                              void* d_out, int out_size, void* d_ws, size_t ws_size,
                              hipStream_t stream) {
    const float* images   = (const float*)d_in[0];
    const int*   H_shifts = (const int*)d_in[1];
    const int*   W_shifts = (const int*)d_in[2];
    float4*      out      = (float4*)d_out;

    constexpr int total_quads = 128 * 3 * 56 * 14;  // 301056 = 1176 * 256
    ds_wrap_translate_kernel<<<dim3(total_quads / 256), dim3(256), 0, stream>>>(
        images, H_shifts, W_shifts, out);
}